// Round 6
// baseline (536.849 us; speedup 1.0000x reference)
//
#include <hip/hip_runtime.h>
#include <math.h>

// UnrolledMeanShift: B=2, D=32, H=W=256, K=5x5, 3 iterations.
// Channel-split: 2 threads/pixel (16 ch each); pair-scalar combined via DPP.
// Patches are iteration-invariant -> stage halo tile in LDS as fp16 ONCE,
// then register-cache each thread's 25x(2 plane) neighbor words ONCE, so the
// 3 iterations run entirely out of registers (zero LDS in iters 2-3).
// dist^2 = |p - z|^2 computed directly: v_pk_add_f16(neg) + v_dot2_f32_f16.
// R6 scratch-proofing (R5 lesson): flat 25-loop, SSA bit_casts, no pointer
// aliasing of locals, no runtime-indexed arrays.

typedef _Float16 h2  __attribute__((ext_vector_type(2)));
typedef _Float16 h8  __attribute__((ext_vector_type(8)));
typedef unsigned int u4v __attribute__((ext_vector_type(4)));

constexpr int Dch  = 32;
constexpr int HH   = 256;
constexpr int WW   = 256;
constexpr int PADp = 2;
constexpr int BH   = 16;
constexpr int BW   = 16;
constexpr int TH   = BH + 2 * PADp;   // 20
constexpr int TWd  = BW + 2 * PADp;   // 20
constexpr int NPIX = TH * TWd;        // 400
constexpr int NPIXP = 402;            // plane-stride pad (bank decorrelation)
constexpr int NCHK = 4;               // 4 planes x 8 fp16 channels
constexpr int ITERS = 3;
constexpr int HWp  = HH * WW;
constexpr int NTHR = 512;             // 2 threads / pixel

__device__ __forceinline__ float fdot2f(h2 a, h2 b, float c) {
    return __builtin_amdgcn_fdot2(a, b, c, false);
}

__device__ __forceinline__ float EXP2F(float x) {
#if __has_builtin(__builtin_amdgcn_exp2f)
    return __builtin_amdgcn_exp2f(x);
#else
    return __expf(x * 0.69314718055994531f);
#endif
}

// value from lane^1 (quad_perm [1,0,3,2]) — pure VALU, no LDS pipe
__device__ __forceinline__ float qswap(float x) {
#if __has_builtin(__builtin_amdgcn_mov_dpp)
    return __int_as_float(
        __builtin_amdgcn_mov_dpp(__float_as_int(x), 0xB1, 0xF, 0xF, true));
#else
    return __shfl_xor(x, 1, 64);
#endif
}

__device__ __forceinline__ h2 as_h2(unsigned int x) {
    return __builtin_bit_cast(h2, x);
}

__global__ __launch_bounds__(NTHR, 4)
void meanshift_kernel(const float* __restrict__ E,
                      const float* __restrict__ lbw,
                      float* __restrict__ out)
{
    __shared__ h8 tile[NCHK][NPIXP];     // 25.7 KB

    const int b   = blockIdx.z;
    const int oh  = blockIdx.y * BH - PADp;
    const int ow  = blockIdx.x * BW - PADp;
    const int tid = threadIdx.x;
    const int half = tid & 1;            // which 16 channels
    const int pix  = tid >> 1;           // 0..255 pixel in tile
    const int px   = pix & (BW - 1);
    const int py   = pix >> 4;
    const int c0   = 2 * half;           // first of my two planes

    const float bwv   = log1pf(__expf(lbw[0]));   // softplus
    const float c2    = 1.0f / (2.0f * bwv * bwv);
    const float negNC = -c2 * 1.44269504f;        // exp2(negNC * dist^2)

    const float* Eb = E + (size_t)b * Dch * HWp;

    // ---- stage halo tile into LDS as fp16 (R3-proven) ----
    for (int job = tid; job < NCHK * NPIX; job += NTHR) {
        const int cc = job / NPIX;
        const int p  = job - cc * NPIX;
        const int tr = p / TWd;
        const int tc = p - tr * TWd;
        const int gh = oh + tr;
        const int gw = ow + tc;
        h8 v;
        if ((unsigned)gh < (unsigned)HH && (unsigned)gw < (unsigned)WW) {
            const float* p0 = Eb + (size_t)(8 * cc) * HWp + gh * WW + gw;
            #pragma unroll
            for (int k = 0; k < 8; ++k) v[k] = (_Float16)p0[k * HWp];
        } else {
            #pragma unroll
            for (int k = 0; k < 8; ++k) v[k] = (_Float16)0.f;
        }
        tile[cc][p] = v;
    }
    __syncthreads();

    // ---- register-cache my 25 neighbors x 2 planes (iteration-invariant) ----
    u4v pcA[25], pcB[25];
    #pragma unroll
    for (int n = 0; n < 25; ++n) {
        const int np_ = (py + n / 5) * TWd + (px + n % 5);
        pcA[n] = __builtin_bit_cast(u4v, tile[c0][np_]);
        pcB[n] = __builtin_bit_cast(u4v, tile[c0 + 1][np_]);
    }

    // ---- init z = own pixel (center neighbor, n=12) ----
    h2 zq[8];
    #pragma unroll
    for (int j = 0; j < 4; ++j) {
        zq[j]     = as_h2(pcA[12][j]);
        zq[4 + j] = as_h2(pcB[12][j]);
    }

    float zf[16];
    #pragma unroll 1
    for (int it = 0; it < ITERS; ++it) {
        float num[16];
        #pragma unroll
        for (int d = 0; d < 16; ++d) num[d] = 0.f;
        float den = 0.f;

        #pragma unroll
        for (int n = 0; n < 25; ++n) {
            const u4v a = pcA[n];
            const u4v bb = pcB[n];
            float s0 = 0.f, s1 = 0.f;
            #pragma unroll
            for (int j = 0; j < 4; ++j) {
                const h2 da = as_h2(a[j])  - zq[j];       // v_pk_add_f16 (neg)
                const h2 db = as_h2(bb[j]) - zq[4 + j];
                s0 = fdot2f(da, da, s0);
                s1 = fdot2f(db, db, s1);
            }
            const float dp   = s0 + s1;                   // my 16 channels
            const float dist = dp + qswap(dp);            // full 32 (symmetric)
            const float w    = EXP2F(dist * negNC);
            den += w;
            #pragma unroll
            for (int j = 0; j < 4; ++j) {
                const h2 pa = as_h2(a[j]);
                const h2 pb = as_h2(bb[j]);
                num[2*j]        = fmaf((float)pa[0], w, num[2*j]);       // v_fma_mix
                num[2*j + 1]    = fmaf((float)pa[1], w, num[2*j + 1]);
                num[8 + 2*j]    = fmaf((float)pb[0], w, num[8 + 2*j]);
                num[8 + 2*j +1] = fmaf((float)pb[1], w, num[8 + 2*j +1]);
            }
        }

        const float inv = 1.0f / (den + 1e-6f);
        #pragma unroll
        for (int d = 0; d < 16; ++d) zf[d] = num[d] * inv;

        if (it < ITERS - 1) {
            // requantize z for next iteration's packed-fp16 diff
            #pragma unroll
            for (int j = 0; j < 8; ++j)
                zq[j] = h2{(_Float16)zf[2*j], (_Float16)zf[2*j + 1]};
        }
    }

    // ---- write out: my 16 channels ----
    float* Ob = out + (size_t)b * Dch * HWp;
    const int off = (oh + PADp + py) * WW + (ow + PADp + px);
    #pragma unroll
    for (int k = 0; k < 16; ++k)
        Ob[(size_t)(16 * half + k) * HWp + off] = zf[k];
}

extern "C" void kernel_launch(void* const* d_in, const int* in_sizes, int n_in,
                              void* d_out, int out_size, void* d_ws, size_t ws_size,
                              hipStream_t stream) {
    const float* E   = (const float*)d_in[0];
    const float* lbw = (const float*)d_in[1];
    float* out       = (float*)d_out;

    const int B = in_sizes[0] / (Dch * HWp);       // = 2
    dim3 grid(WW / BW, HH / BH, B);                // (16,16,2) = 512 blocks
    dim3 block(NTHR, 1, 1);                        // 512 threads (2/pixel)
    hipLaunchKernelGGL(meanshift_kernel, grid, block, 0, stream, E, lbw, out);
}

// Round 7
// 35.933 us; speedup vs baseline: 14.9401x; 14.9401x over previous
//
#include <hip/hip_runtime.h>
#include <math.h>

// UnrolledMeanShift: B=2, D=32, H=W=256, K=5x5, 3 iterations.
// R7 = R3's proven skeleton (2 thr/pixel, 16 ch each, DPP pair-combine,
// fp16 LDS halo tile staged once) with the VALU fat removed:
//  - numerator in PACKED fp16 as NAMED h2 SSA vars n0..n7 (v_pk_fma_f16)
//  - direct |p-z|^2 via v_pk_add_f16(neg) + v_dot2_f32_f16 (sqv path deleted)
//  - z as named packed h2 z0..z7
// NO per-thread arrays anywhere (R4/R5/R6 all died to scratch-allocated
// aggregates: 816MB FETCH in R6 was pcA/pcB[25] in local memory).

typedef _Float16 h2  __attribute__((ext_vector_type(2)));
typedef _Float16 h8  __attribute__((ext_vector_type(8)));
typedef unsigned int u4v __attribute__((ext_vector_type(4)));

constexpr int Dch  = 32;
constexpr int HH   = 256;
constexpr int WW   = 256;
constexpr int PADp = 2;
constexpr int BH   = 16;
constexpr int BW   = 16;
constexpr int TH   = BH + 2 * PADp;   // 20
constexpr int TWd  = BW + 2 * PADp;   // 20
constexpr int NPIX = TH * TWd;        // 400
constexpr int NPIXP = 402;            // plane-stride pad (bank decorrelation)
constexpr int NCHK = 4;               // 4 planes x 8 fp16 channels
constexpr int ITERS = 3;
constexpr int HWp  = HH * WW;
constexpr int NTHR = 512;             // 2 threads / pixel

__device__ __forceinline__ float fdot2f(h2 a, h2 b, float c) {
    return __builtin_amdgcn_fdot2(a, b, c, false);
}

__device__ __forceinline__ float EXP2F(float x) {
#if __has_builtin(__builtin_amdgcn_exp2f)
    return __builtin_amdgcn_exp2f(x);
#else
    return __expf(x * 0.69314718055994531f);
#endif
}

// value from lane^1 (quad_perm [1,0,3,2]) — pure VALU, no LDS pipe
__device__ __forceinline__ float qswap(float x) {
#if __has_builtin(__builtin_amdgcn_mov_dpp)
    return __int_as_float(
        __builtin_amdgcn_mov_dpp(__float_as_int(x), 0xB1, 0xF, 0xF, true));
#else
    return __shfl_xor(x, 1, 64);
#endif
}

__device__ __forceinline__ h2 as_h2(unsigned int x) {
    return __builtin_bit_cast(h2, x);
}

__global__ __launch_bounds__(NTHR, 4)
void meanshift_kernel(const float* __restrict__ E,
                      const float* __restrict__ lbw,
                      float* __restrict__ out)
{
    __shared__ u4v tile[NCHK][NPIXP];    // 25.7 KB (fp16, 8 ch per 16B word)

    const int b    = blockIdx.z;
    const int oh   = blockIdx.y * BH - PADp;
    const int ow   = blockIdx.x * BW - PADp;
    const int tid  = threadIdx.x;
    const int half = tid & 1;            // which 16 channels
    const int pix  = tid >> 1;           // 0..255 pixel in tile
    const int px   = pix & (BW - 1);
    const int py   = pix >> 4;
    const int c0   = 2 * half;           // first of my two planes

    const float bwv   = log1pf(__expf(lbw[0]));   // softplus
    const float cc2   = 1.0f / (2.0f * bwv * bwv);
    const float negNC = -cc2 * 1.44269504f;       // w = exp2(negNC * dist^2)

    const float* Eb = E + (size_t)b * Dch * HWp;

    // ---- stage halo tile into LDS as fp16 (R3-proven) ----
    for (int job = tid; job < NCHK * NPIX; job += NTHR) {
        const int cc = job / NPIX;
        const int p  = job - cc * NPIX;
        const int tr = p / TWd;
        const int tc = p - tr * TWd;
        const int gh = oh + tr;
        const int gw = ow + tc;
        h8 v;
        if ((unsigned)gh < (unsigned)HH && (unsigned)gw < (unsigned)WW) {
            const float* p0 = Eb + (size_t)(8 * cc) * HWp + gh * WW + gw;
            #pragma unroll
            for (int k = 0; k < 8; ++k) v[k] = (_Float16)p0[k * HWp];
        } else {
            #pragma unroll
            for (int k = 0; k < 8; ++k) v[k] = (_Float16)0.f;
        }
        tile[cc][p] = __builtin_bit_cast(u4v, v);
    }
    __syncthreads();

    const u4v* __restrict__ tA = tile[c0];
    const u4v* __restrict__ tB = tile[c0 + 1];

    // ---- init z = own pixel, my 16 channels (named packed h2) ----
    const int myp = (py + PADp) * TWd + (px + PADp);
    h2 z0, z1, z2, z3, z4, z5, z6, z7;
    {
        const u4v ca = tA[myp];
        const u4v cb = tB[myp];
        z0 = as_h2(ca[0]); z1 = as_h2(ca[1]); z2 = as_h2(ca[2]); z3 = as_h2(ca[3]);
        z4 = as_h2(cb[0]); z5 = as_h2(cb[1]); z6 = as_h2(cb[2]); z7 = as_h2(cb[3]);
    }

    float* Ob = out + (size_t)b * Dch * HWp;
    const int off    = (oh + PADp + py) * WW + (ow + PADp + px);
    const int chbase = 16 * half;

#define NBODY(NPI) do {                                                       \
        const u4v a  = tA[(NPI)];                                             \
        const u4v bq = tB[(NPI)];                                             \
        const h2 pa0 = as_h2(a[0]),  pa1 = as_h2(a[1]);                       \
        const h2 pa2 = as_h2(a[2]),  pa3 = as_h2(a[3]);                       \
        const h2 pb0 = as_h2(bq[0]), pb1 = as_h2(bq[1]);                      \
        const h2 pb2 = as_h2(bq[2]), pb3 = as_h2(bq[3]);                      \
        const h2 e0 = pa0 - z0, e1 = pa1 - z1, e2 = pa2 - z2, e3 = pa3 - z3;  \
        const h2 f0 = pb0 - z4, f1 = pb1 - z5, f2 = pb2 - z6, f3 = pb3 - z7;  \
        float s0 = fdot2f(e0, e0, 0.f);                                       \
        s0 = fdot2f(e1, e1, s0); s0 = fdot2f(e2, e2, s0);                     \
        s0 = fdot2f(e3, e3, s0);                                              \
        float s1 = fdot2f(f0, f0, 0.f);                                       \
        s1 = fdot2f(f1, f1, s1); s1 = fdot2f(f2, f2, s1);                     \
        s1 = fdot2f(f3, f3, s1);                                              \
        const float dp   = s0 + s1;                                           \
        const float dist = dp + qswap(dp);                                    \
        const float w    = EXP2F(dist * negNC);                               \
        den += w;                                                             \
        const _Float16 wh = (_Float16)w;                                      \
        const h2 w2v = {wh, wh};                                              \
        n0 += pa0 * w2v; n1 += pa1 * w2v; n2 += pa2 * w2v; n3 += pa3 * w2v;   \
        n4 += pb0 * w2v; n5 += pb1 * w2v; n6 += pb2 * w2v; n7 += pb3 * w2v;   \
    } while (0)

    #pragma unroll 1
    for (int it = 0; it < ITERS; ++it) {
        h2 n0 = {(_Float16)0.f, (_Float16)0.f};
        h2 n1 = n0, n2 = n0, n3 = n0, n4 = n0, n5 = n0, n6 = n0, n7 = n0;
        float den = 0.f;

        #pragma unroll 1
        for (int di = 0; di < 5; ++di) {
            const int rb = (py + di) * TWd + px;
            NBODY(rb + 0);
            NBODY(rb + 1);
            NBODY(rb + 2);
            NBODY(rb + 3);
            NBODY(rb + 4);
        }

        const float invf = 1.0f / (den + 1e-6f);
        if (it == ITERS - 1) {
            // final: f32 divide, write out my 16 channels
#define WR(IDX, NV, EL) Ob[(size_t)(chbase + (IDX)) * HWp + off] = (float)NV[EL] * invf
            WR(0,  n0, 0); WR(1,  n0, 1); WR(2,  n1, 0); WR(3,  n1, 1);
            WR(4,  n2, 0); WR(5,  n2, 1); WR(6,  n3, 0); WR(7,  n3, 1);
            WR(8,  n4, 0); WR(9,  n4, 1); WR(10, n5, 0); WR(11, n5, 1);
            WR(12, n6, 0); WR(13, n6, 1); WR(14, n7, 0); WR(15, n7, 1);
#undef WR
        } else {
            const _Float16 ih = (_Float16)invf;
            const h2 iv = {ih, ih};
            z0 = n0 * iv; z1 = n1 * iv; z2 = n2 * iv; z3 = n3 * iv;
            z4 = n4 * iv; z5 = n5 * iv; z6 = n6 * iv; z7 = n7 * iv;
        }
    }
#undef NBODY
}

extern "C" void kernel_launch(void* const* d_in, const int* in_sizes, int n_in,
                              void* d_out, int out_size, void* d_ws, size_t ws_size,
                              hipStream_t stream) {
    const float* E   = (const float*)d_in[0];
    const float* lbw = (const float*)d_in[1];
    float* out       = (float*)d_out;

    const int B = in_sizes[0] / (Dch * HWp);       // = 2
    dim3 grid(WW / BW, HH / BH, B);                // (16,16,2) = 512 blocks
    dim3 block(NTHR, 1, 1);                        // 512 threads (2/pixel)
    hipLaunchKernelGGL(meanshift_kernel, grid, block, 0, stream, E, lbw, out);
}